// Round 1
// baseline (570.750 us; speedup 1.0000x reference)
//
#include <hip/hip_runtime.h>

// InterNet: B=32, N=16 objects, D=64 ch, P=8 (64 px), PAIRS=240.
// Factorization: conv(mask*[y1;y2], W_rel) = mask*(conv(x[o1],W_rel[:,:64]) +
// conv(x[o2],W_rel[:,64:])) -- 15x FLOP cut on the dominant pair conv.

#define NIMG 512          // B * N
#define IMGSZ 4096        // 64 ch * 64 px

// Generic direct conv 64->64 on one 8x8 image per block (256 threads).
// W indexed as W[oc*WSTRIDE + ic*9 + k] (pass W pre-offset for the ic-half).
template<bool RELU, bool HAS_BIAS, int WSTRIDE>
__global__ __launch_bounds__(256) void conv64_kernel(
    const float* __restrict__ in,     // [NIMG][64][64]
    const float* __restrict__ W,
    const float* __restrict__ bias,   // [64] or unused
    float* __restrict__ out)          // [NIMG][64][64]
{
  __shared__ float smem[64 * 100];    // [ic][10][10] zero-padded, 25.6 KB
  const int img = blockIdx.x;
  const float* ib = in + (size_t)img * IMGSZ;
  for (int idx = threadIdx.x; idx < 6400; idx += 256) {
    int ic = idx / 100;
    int rem = idx - ic * 100;
    int iy = rem / 10, ix = rem - iy * 10;
    float v = 0.f;
    if (iy >= 1 && iy <= 8 && ix >= 1 && ix <= 8)
      v = ib[ic * 64 + (iy - 1) * 8 + (ix - 1)];
    smem[idx] = v;
  }
  __syncthreads();

  const int pix = threadIdx.x & 63;
  const int py = pix >> 3, px = pix & 7;
  const int oc0 = __builtin_amdgcn_readfirstlane((threadIdx.x >> 6) << 4);

  float acc[16];
#pragma unroll
  for (int r = 0; r < 16; ++r) {
    if constexpr (HAS_BIAS) acc[r] = bias[oc0 + r];
    else acc[r] = 0.f;
  }

  const int base_off = py * 10 + px;  // padded coord of (py-1, px-1)
  for (int ic = 0; ic < 64; ++ic) {
    float v[9];
    const float* sp = smem + ic * 100 + base_off;
#pragma unroll
    for (int ky = 0; ky < 3; ++ky)
#pragma unroll
      for (int kx = 0; kx < 3; ++kx)
        v[ky * 3 + kx] = sp[ky * 10 + kx];
    const float* wp = W + (size_t)oc0 * WSTRIDE + ic * 9;
#pragma unroll
    for (int r = 0; r < 16; ++r) {
#pragma unroll
      for (int k = 0; k < 9; ++k)
        acc[r] += v[k] * wp[r * WSTRIDE + k];
    }
  }

  float* ob = out + (size_t)img * IMGSZ;
#pragma unroll
  for (int r = 0; r < 16; ++r) {
    float v2 = acc[r];
    if constexpr (RELU) v2 = fmaxf(v2, 0.f);
    ob[(oc0 + r) * 64 + pix] = v2;
  }
}

// Conv with 128 input channels from two 64-ch sources (concat without
// materializing). W indexed [oc*1152 + ic*9 + k], ic in [0,128).
template<bool RELU>
__global__ __launch_bounds__(256) void conv128_kernel(
    const float* __restrict__ inA,    // ic 0..63
    const float* __restrict__ inB,    // ic 64..127
    const float* __restrict__ W,
    const float* __restrict__ bias,
    float* __restrict__ out)
{
  __shared__ float smem[128 * 100];   // 51.2 KB
  const int img = blockIdx.x;
  for (int idx = threadIdx.x; idx < 12800; idx += 256) {
    int ic = idx / 100;
    int rem = idx - ic * 100;
    int iy = rem / 10, ix = rem - iy * 10;
    float v = 0.f;
    if (iy >= 1 && iy <= 8 && ix >= 1 && ix <= 8) {
      const float* src = (ic < 64)
          ? (inA + (size_t)img * IMGSZ + ic * 64)
          : (inB + (size_t)img * IMGSZ + (ic - 64) * 64);
      v = src[(iy - 1) * 8 + (ix - 1)];
    }
    smem[idx] = v;
  }
  __syncthreads();

  const int pix = threadIdx.x & 63;
  const int py = pix >> 3, px = pix & 7;
  const int oc0 = __builtin_amdgcn_readfirstlane((threadIdx.x >> 6) << 4);

  float acc[16];
#pragma unroll
  for (int r = 0; r < 16; ++r) acc[r] = bias[oc0 + r];

  const int base_off = py * 10 + px;
  for (int ic = 0; ic < 128; ++ic) {
    float v[9];
    const float* sp = smem + ic * 100 + base_off;
#pragma unroll
    for (int ky = 0; ky < 3; ++ky)
#pragma unroll
      for (int kx = 0; kx < 3; ++kx)
        v[ky * 3 + kx] = sp[ky * 10 + kx];
    const float* wp = W + (size_t)oc0 * 1152 + ic * 9;
#pragma unroll
    for (int r = 0; r < 16; ++r) {
#pragma unroll
      for (int k = 0; k < 9; ++k)
        acc[r] += v[k] * wp[r * 1152 + k];
    }
  }

  float* ob = out + (size_t)img * IMGSZ;
#pragma unroll
  for (int r = 0; r < 16; ++r) {
    float v2 = acc[r];
    if constexpr (RELU) v2 = fmaxf(v2, 0.f);
    ob[(oc0 + r) * 64 + pix] = v2;
  }
}

// Pair combine + scatter-sum: accum[b,i] += sum_j relu(m*(cA[o1]+cB[o2])+b_rel)
__global__ __launch_bounds__(256) void combine_kernel(
    const float* __restrict__ cA, const float* __restrict__ cB,
    const int* __restrict__ g_idx, const float* __restrict__ b_rel,
    float* __restrict__ accum)
{
  const int b = blockIdx.x >> 4;
  const int i = blockIdx.x & 15;
  __shared__ int so1[15], so2[15];
  __shared__ float sm[15];
  if (threadIdx.x < 15) {
    const int* gp = g_idx + ((size_t)b * 240 + i * 15 + threadIdx.x) * 3;
    so1[threadIdx.x] = gp[0] & 15;   // idx % 16 (tile semantics), 16 = pow2
    so2[threadIdx.x] = gp[1] & 15;
    sm[threadIdx.x] = (float)gp[2];
  }
  __syncthreads();

  const float* cAb = cA + (size_t)b * 16 * IMGSZ;
  const float* cBb = cB + (size_t)b * 16 * IMGSZ;
  float* ap = accum + ((size_t)b * 16 + i) * IMGSZ;

  float acc[16], brel[16];
#pragma unroll
  for (int r = 0; r < 16; ++r) {
    int e = threadIdx.x + r * 256;
    acc[r] = ap[e];                  // xs (self conv result)
    brel[r] = b_rel[e >> 6];
  }
  for (int j = 0; j < 15; ++j) {
    const float* a1 = cAb + so1[j] * IMGSZ;
    const float* a2 = cBb + so2[j] * IMGSZ;
    float m = sm[j];
#pragma unroll
    for (int r = 0; r < 16; ++r) {
      int e = threadIdx.x + r * 256;
      float v = m * (a1[e] + a2[e]) + brel[r];
      acc[r] += fmaxf(v, 0.f);
    }
  }
#pragma unroll
  for (int r = 0; r < 16; ++r) ap[threadIdx.x + r * 256] = acc[r];
}

extern "C" void kernel_launch(void* const* d_in, const int* in_sizes, int n_in,
                              void* d_out, int out_size, void* d_ws, size_t ws_size,
                              hipStream_t stream) {
  const float* x      = (const float*)d_in[0];
  const int*   g_idx  = (const int*)  d_in[1];
  const float* W_rel  = (const float*)d_in[2];
  const float* b_rel  = (const float*)d_in[3];
  const float* W_self = (const float*)d_in[4];
  const float* b_self = (const float*)d_in[5];
  const float* W_aff  = (const float*)d_in[6];
  const float* b_aff  = (const float*)d_in[7];
  const float* W_agg  = (const float*)d_in[8];
  const float* b_agg  = (const float*)d_in[9];
  float* out = (float*)d_out;

  float* ws    = (float*)d_ws;
  float* cA    = ws;                       // 2,097,152 floats
  float* cB    = ws + 2097152;
  float* accum = ws + 2 * 2097152;
  float* abuf  = ws;                       // reuse cA after combine
  // total ws: 24 MB

  // xs = conv_relu(x, W_self) -> accum
  conv64_kernel<true, true, 576><<<NIMG, 256, 0, stream>>>(x, W_self, b_self, accum);
  // cA = conv(x, W_rel[:, :64]) (no bias/relu)
  conv64_kernel<false, false, 1152><<<NIMG, 256, 0, stream>>>(x, W_rel, nullptr, cA);
  // cB = conv(x, W_rel[:, 64:])
  conv64_kernel<false, false, 1152><<<NIMG, 256, 0, stream>>>(x, W_rel + 64 * 9, nullptr, cB);
  // accum += scatter-sum of relu(mask*(cA[o1]+cB[o2]) + b_rel)
  combine_kernel<<<NIMG, 256, 0, stream>>>(cA, cB, g_idx, b_rel, accum);
  // a = conv_relu(accum, W_aff) -> abuf
  conv64_kernel<true, true, 576><<<NIMG, 256, 0, stream>>>(accum, W_aff, b_aff, abuf);
  // out = conv_relu(concat[a, x], W_agg)
  conv128_kernel<true><<<NIMG, 256, 0, stream>>>(abuf, x, W_agg, b_agg, out);
}

// Round 2
// 177.119 us; speedup vs baseline: 3.2224x; 3.2224x over previous
//
#include <hip/hip_runtime.h>

// InterNet B=32,N=16,D=64,P=8. Factorized: conv(mask*[y1;y2],W_rel) =
// mask*(convA(x[o1]) + convB(x[o2])). All convs as bf16 MFMA (fp32 accum):
// 9 shifted GEMMs, out[oc][px] = sum_tap sum_ic Wt[tap][oc][ic]*img[ic][spx].

#define NIMG 512
#define IMGSZ 4096

using bf16x8 = __attribute__((ext_vector_type(8))) short;
using f32x4  = __attribute__((ext_vector_type(4))) float;

__device__ inline unsigned short f2bf(float f) {
  union { float f; unsigned u; } v; v.f = f;
  unsigned r = v.u + 0x7fffu + ((v.u >> 16) & 1u);
  return (unsigned short)(r >> 16);
}

// Wt layout: convs 0..3 (self,relA,relB,aff): [9][64][64] at c*36864.
// agg: [9][64][128] at 4*36864. All bf16.
__global__ __launch_bounds__(256) void prep_weights(
    const float* __restrict__ Wr, const float* __restrict__ Ws,
    const float* __restrict__ Wa, const float* __restrict__ Wg,
    unsigned short* __restrict__ Wt)
{
  int idx = blockIdx.x * 256 + threadIdx.x;
  if (idx >= 221184) return;
  float v;
  if (idx < 147456) {
    int c = idx / 36864, r = idx % 36864;
    int t = r >> 12, oc = (r >> 6) & 63, ic = r & 63;
    switch (c) {
      case 0:  v = Ws[oc * 576 + ic * 9 + t]; break;
      case 1:  v = Wr[oc * 1152 + ic * 9 + t]; break;
      case 2:  v = Wr[oc * 1152 + (ic + 64) * 9 + t]; break;
      default: v = Wa[oc * 576 + ic * 9 + t]; break;
    }
  } else {
    int r2 = idx - 147456;
    int t = r2 >> 13, oc = (r2 >> 7) & 63, ic = r2 & 127;
    v = Wg[oc * 1152 + ic * 9 + t];
  }
  Wt[idx] = f2bf(v);
}

// One image per block, 512 threads = 8 waves. Wave w: oc-tile (w>>1)*16,
// px-half (w&1)*32 (2 n-tiles). LDS image [px][ic] bf16, row ROW=NIC+8
// (odd 16B-chunk stride -> conflict-free ds_read_b128). Row 64 = zeros
// for out-of-bounds taps.
template<int NIC, bool RB>
__global__ __launch_bounds__(512) void conv_mfma(
    const float* __restrict__ src0, const float* __restrict__ src1,
    const unsigned short* __restrict__ Wt,   // [9][64][NIC] bf16
    const float* __restrict__ bias,
    float* __restrict__ out)
{
  constexpr int ROW = NIC + 8;
  __shared__ __align__(16) unsigned short simg[65 * ROW];
  const int img = blockIdx.x;
  const int tid = threadIdx.x;
  const int w = tid >> 6, lane = tid & 63;

  // ---- stage: [ic][px] fp32 -> LDS [px][ic] bf16 (pairs packed as dword)
  {
    const int px = lane;
    const float* base0 = src0 + (size_t)img * IMGSZ;
#pragma unroll
    for (int r = 0; r < NIC / 16; ++r) {
      int ic0 = (w + 8 * r) * 2;
      const float* s;
      if (NIC == 128 && ic0 >= 64) s = src1 + (size_t)img * IMGSZ + (ic0 - 64) * 64;
      else                         s = base0 + ic0 * 64;
      float a = s[px], b = s[64 + px];
      unsigned pk = (unsigned)f2bf(a) | ((unsigned)f2bf(b) << 16);
      *(unsigned*)(simg + px * ROW + ic0) = pk;
    }
    if (tid < ROW / 2) ((unsigned*)simg)[(64 * ROW) / 2 + tid] = 0;
  }
  __syncthreads();

  const int q = lane >> 4, n16 = lane & 15;
  const int ocb = (w >> 1) * 16;
  const int pxb = (w & 1) * 32;
  const int px0 = pxb + n16, px1 = pxb + 16 + n16;
  const int py0 = px0 >> 3, pxx0 = px0 & 7;
  const int py1 = px1 >> 3, pxx1 = px1 & 7;

  f32x4 acc0 = {0.f, 0.f, 0.f, 0.f};
  f32x4 acc1 = {0.f, 0.f, 0.f, 0.f};

  const unsigned short* Abase = Wt + (ocb + n16) * NIC + q * 8;

#pragma unroll
  for (int tap = 0; tap < 9; ++tap) {
    const int dy = tap / 3 - 1, dx = tap % 3 - 1;
    int sy0 = py0 + dy, sx0 = pxx0 + dx;
    int sy1 = py1 + dy, sx1 = pxx1 + dx;
    int sp0 = ((unsigned)sy0 < 8u && (unsigned)sx0 < 8u) ? (sy0 * 8 + sx0) : 64;
    int sp1 = ((unsigned)sy1 < 8u && (unsigned)sx1 < 8u) ? (sy1 * 8 + sx1) : 64;
    const unsigned short* b0p = simg + sp0 * ROW + q * 8;
    const unsigned short* b1p = simg + sp1 * ROW + q * 8;
    const unsigned short* ap  = Abase + tap * 64 * NIC;
#pragma unroll
    for (int ks = 0; ks < NIC / 32; ++ks) {
      bf16x8 a  = *(const bf16x8*)(ap  + ks * 32);
      bf16x8 b0 = *(const bf16x8*)(b0p + ks * 32);
      bf16x8 b1 = *(const bf16x8*)(b1p + ks * 32);
      acc0 = __builtin_amdgcn_mfma_f32_16x16x32_bf16(a, b0, acc0, 0, 0, 0);
      acc1 = __builtin_amdgcn_mfma_f32_16x16x32_bf16(a, b1, acc1, 0, 0, 0);
    }
  }

  // ---- epilogue: D row = q*4+r (oc), col = n16 (px)
  float* ob = out + (size_t)img * IMGSZ;
#pragma unroll
  for (int r = 0; r < 4; ++r) {
    int oc = ocb + q * 4 + r;
    float bv = RB ? bias[oc] : 0.f;
    float v0 = acc0[r] + bv, v1 = acc1[r] + bv;
    if (RB) { v0 = fmaxf(v0, 0.f); v1 = fmaxf(v1, 0.f); }
    ob[oc * 64 + px0] = v0;
    ob[oc * 64 + px1] = v1;
  }
}

// accum[b,i] += sum_j relu(m*(cA[o1]+cB[o2])+b_rel)   (fp32, unchanged)
__global__ __launch_bounds__(256) void combine_kernel(
    const float* __restrict__ cA, const float* __restrict__ cB,
    const int* __restrict__ g_idx, const float* __restrict__ b_rel,
    float* __restrict__ accum)
{
  const int b = blockIdx.x >> 4;
  const int i = blockIdx.x & 15;
  __shared__ int so1[15], so2[15];
  __shared__ float sm[15];
  if (threadIdx.x < 15) {
    const int* gp = g_idx + ((size_t)b * 240 + i * 15 + threadIdx.x) * 3;
    so1[threadIdx.x] = gp[0] & 15;
    so2[threadIdx.x] = gp[1] & 15;
    sm[threadIdx.x] = (float)gp[2];
  }
  __syncthreads();

  const float* cAb = cA + (size_t)b * 16 * IMGSZ;
  const float* cBb = cB + (size_t)b * 16 * IMGSZ;
  float* ap = accum + ((size_t)b * 16 + i) * IMGSZ;

  float acc[16], brel[16];
#pragma unroll
  for (int r = 0; r < 16; ++r) {
    int e = threadIdx.x + r * 256;
    acc[r] = ap[e];
    brel[r] = b_rel[e >> 6];
  }
  for (int j = 0; j < 15; ++j) {
    const float* a1 = cAb + so1[j] * IMGSZ;
    const float* a2 = cBb + so2[j] * IMGSZ;
    float m = sm[j];
#pragma unroll
    for (int r = 0; r < 16; ++r) {
      int e = threadIdx.x + r * 256;
      float v = m * (a1[e] + a2[e]) + brel[r];
      acc[r] += fmaxf(v, 0.f);
    }
  }
#pragma unroll
  for (int r = 0; r < 16; ++r) ap[threadIdx.x + r * 256] = acc[r];
}

extern "C" void kernel_launch(void* const* d_in, const int* in_sizes, int n_in,
                              void* d_out, int out_size, void* d_ws, size_t ws_size,
                              hipStream_t stream) {
  const float* x      = (const float*)d_in[0];
  const int*   g_idx  = (const int*)  d_in[1];
  const float* W_rel  = (const float*)d_in[2];
  const float* b_rel  = (const float*)d_in[3];
  const float* W_self = (const float*)d_in[4];
  const float* b_self = (const float*)d_in[5];
  const float* W_aff  = (const float*)d_in[6];
  const float* b_aff  = (const float*)d_in[7];
  const float* W_agg  = (const float*)d_in[8];
  const float* b_agg  = (const float*)d_in[9];
  float* out = (float*)d_out;

  float* ws    = (float*)d_ws;
  float* cA    = ws;
  float* cB    = ws + 2097152;
  float* accum = ws + 2 * 2097152;
  float* abuf  = cA;                       // reuse after combine
  unsigned short* Wt = (unsigned short*)(ws + 3 * 2097152);  // 221184 bf16

  prep_weights<<<864, 256, 0, stream>>>(W_rel, W_self, W_aff, W_agg, Wt);
  // xs = conv_relu(x, W_self) -> accum
  conv_mfma<64, true ><<<NIMG, 512, 0, stream>>>(x, nullptr, Wt,             b_self, accum);
  // cA/cB = half convs of W_rel (no bias/relu)
  conv_mfma<64, false><<<NIMG, 512, 0, stream>>>(x, nullptr, Wt + 36864,     nullptr, cA);
  conv_mfma<64, false><<<NIMG, 512, 0, stream>>>(x, nullptr, Wt + 2 * 36864, nullptr, cB);
  // accum += scatter-sum relu(mask*(cA[o1]+cB[o2]) + b_rel)
  combine_kernel<<<NIMG, 256, 0, stream>>>(cA, cB, g_idx, b_rel, accum);
  // a = conv_relu(accum, W_aff) -> abuf
  conv_mfma<64, true ><<<NIMG, 512, 0, stream>>>(accum, nullptr, Wt + 3 * 36864, b_aff, abuf);
  // out = conv_relu(concat[a, x], W_agg)
  conv_mfma<128, true><<<NIMG, 512, 0, stream>>>(abuf, x, Wt + 4 * 36864, b_agg, out);
}

// Round 3
// 147.339 us; speedup vs baseline: 3.8737x; 1.2021x over previous
//
#include <hip/hip_runtime.h>

// InterNet B=32,N=16,D=64,P=8. Factorized: conv(mask*[y1;y2],W_rel) =
// mask*(convA(x[o1]) + convB(x[o2])). 3 dispatches:
//   prep: weights -> bf16 [tap][oc][ic]
//   k1:   per image: stage x once, MFMA self/relA/relB convs -> xs,cA,cB (fp32, [px][ic])
//   k2:   per image: combine(+scatter-sum) -> pred(LDS) -> aff conv -> a(LDS) -> agg conv -> out

#define NIMG 512
#define IMGSZ 4096

using bf16x8 = __attribute__((ext_vector_type(8))) short;
using f32x4  = __attribute__((ext_vector_type(4))) float;
using u16x8  = __attribute__((ext_vector_type(8))) unsigned short;

__device__ inline unsigned short f2bf(float f) {
  union { float f; unsigned u; } v; v.f = f;
  unsigned r = v.u + 0x7fffu + ((v.u >> 16) & 1u);
  return (unsigned short)(r >> 16);
}

// Wt: convs 0..3 (self,relA,relB,aff) [9][64][64] at c*36864; agg [9][64][128] at 4*36864.
__global__ __launch_bounds__(256) void prep_weights(
    const float* __restrict__ Wr, const float* __restrict__ Ws,
    const float* __restrict__ Wa, const float* __restrict__ Wg,
    unsigned short* __restrict__ Wt)
{
  int idx = blockIdx.x * 256 + threadIdx.x;
  if (idx >= 221184) return;
  float v;
  if (idx < 147456) {
    int c = idx / 36864, r = idx % 36864;
    int t = r >> 12, oc = (r >> 6) & 63, ic = r & 63;
    switch (c) {
      case 0:  v = Ws[oc * 576 + ic * 9 + t]; break;
      case 1:  v = Wr[oc * 1152 + ic * 9 + t]; break;
      case 2:  v = Wr[oc * 1152 + (ic + 64) * 9 + t]; break;
      default: v = Wa[oc * 576 + ic * 9 + t]; break;
    }
  } else {
    int r2 = idx - 147456;
    int t = r2 >> 13, oc = (r2 >> 7) & 63, ic = r2 & 127;
    v = Wg[oc * 1152 + ic * 9 + t];
  }
  Wt[idx] = f2bf(v);
}

// XCD swizzle: batch b pinned to XCD b&7 (blockIdx%8 heuristic; perf-only).
__device__ inline void decode_img(int j, int& b, int& o) {
  b = ((j >> 7) << 3) | (j & 7);
  o = (j >> 3) & 15;
}

__global__ __launch_bounds__(512) void k1_convs(
    const float* __restrict__ x,
    const unsigned short* __restrict__ Wt,
    const float* __restrict__ b_self,
    float* __restrict__ xs, float* __restrict__ cA, float* __restrict__ cB)
{
  constexpr int ROW = 72;
  __shared__ __align__(16) unsigned short simg[65 * ROW];
  int b, o;
  decode_img(blockIdx.x, b, o);
  const int img = b * 16 + o;
  const int tid = threadIdx.x;
  const int w = tid >> 6, lane = tid & 63;

  // stage x [ic][px] fp32 -> LDS [px][ic] bf16; row 64 = zeros
  {
    const int px = lane;
    const float* base = x + (size_t)img * IMGSZ;
#pragma unroll
    for (int r = 0; r < 4; ++r) {
      int ic0 = (w + 8 * r) * 2;
      const float* s = base + ic0 * 64;
      float a = s[px], c = s[64 + px];
      *(unsigned*)(simg + px * ROW + ic0) = (unsigned)f2bf(a) | ((unsigned)f2bf(c) << 16);
    }
    if (tid < ROW / 2) ((unsigned*)simg)[(64 * ROW) / 2 + tid] = 0;
  }
  __syncthreads();

  const int q = lane >> 4, n16 = lane & 15;
  const int ocb = (w >> 1) * 16;
  const int pxb = (w & 1) * 32;
  const int px0 = pxb + n16, px1 = px0 + 16;
  const int py0 = px0 >> 3, pxx0 = px0 & 7;
  const int py1 = px1 >> 3, pxx1 = px1 & 7;

  f32x4 aS0{}, aS1{}, aA0{}, aA1{}, aB0{}, aB1{};
  const int awoff = (ocb + n16) * 64 + q * 8;
  const unsigned short* WS = Wt + awoff;
  const unsigned short* WA = Wt + 36864 + awoff;
  const unsigned short* WB = Wt + 2 * 36864 + awoff;

#pragma unroll
  for (int tap = 0; tap < 9; ++tap) {
    const int dy = tap / 3 - 1, dx = tap % 3 - 1;
    int sy0 = py0 + dy, sx0 = pxx0 + dx;
    int sy1 = py1 + dy, sx1 = pxx1 + dx;
    int sp0 = ((unsigned)sy0 < 8u && (unsigned)sx0 < 8u) ? (sy0 * 8 + sx0) : 64;
    int sp1 = ((unsigned)sy1 < 8u && (unsigned)sx1 < 8u) ? (sy1 * 8 + sx1) : 64;
#pragma unroll
    for (int ks = 0; ks < 2; ++ks) {
      bf16x8 b0 = *(const bf16x8*)(simg + sp0 * ROW + q * 8 + ks * 32);
      bf16x8 b1 = *(const bf16x8*)(simg + sp1 * ROW + q * 8 + ks * 32);
      const int wo = tap * 4096 + ks * 32;
      bf16x8 as = *(const bf16x8*)(WS + wo);
      bf16x8 aa = *(const bf16x8*)(WA + wo);
      bf16x8 ab = *(const bf16x8*)(WB + wo);
      aS0 = __builtin_amdgcn_mfma_f32_16x16x32_bf16(as, b0, aS0, 0, 0, 0);
      aS1 = __builtin_amdgcn_mfma_f32_16x16x32_bf16(as, b1, aS1, 0, 0, 0);
      aA0 = __builtin_amdgcn_mfma_f32_16x16x32_bf16(aa, b0, aA0, 0, 0, 0);
      aA1 = __builtin_amdgcn_mfma_f32_16x16x32_bf16(aa, b1, aA1, 0, 0, 0);
      aB0 = __builtin_amdgcn_mfma_f32_16x16x32_bf16(ab, b0, aB0, 0, 0, 0);
      aB1 = __builtin_amdgcn_mfma_f32_16x16x32_bf16(ab, b1, aB1, 0, 0, 0);
    }
  }

  // epilogue -> fp32 [px][ic], float4 per frag (oc = ocb + q*4 + r)
  const size_t ib = (size_t)img * IMGSZ;
  const int co = ocb + q * 4;
  f32x4 vs0 = aS0, vs1 = aS1;
#pragma unroll
  for (int r = 0; r < 4; ++r) {
    float bv = b_self[co + r];
    vs0[r] = fmaxf(vs0[r] + bv, 0.f);
    vs1[r] = fmaxf(vs1[r] + bv, 0.f);
  }
  *(f32x4*)(xs + ib + px0 * 64 + co) = vs0;
  *(f32x4*)(xs + ib + px1 * 64 + co) = vs1;
  *(f32x4*)(cA + ib + px0 * 64 + co) = aA0;
  *(f32x4*)(cA + ib + px1 * 64 + co) = aA1;
  *(f32x4*)(cB + ib + px0 * 64 + co) = aB0;
  *(f32x4*)(cB + ib + px1 * 64 + co) = aB1;
}

__global__ __launch_bounds__(512) void k2_fused(
    const float* __restrict__ x,
    const int* __restrict__ g_idx,
    const unsigned short* __restrict__ Wt,
    const float* __restrict__ b_rel, const float* __restrict__ b_aff,
    const float* __restrict__ b_agg,
    const float* __restrict__ xs, const float* __restrict__ cA,
    const float* __restrict__ cB,
    float* __restrict__ out)
{
  constexpr int ROW = 72, ROW2 = 136;
  __shared__ __align__(16) unsigned short simg[65 * ROW];    // pred (64 ic)
  __shared__ __align__(16) unsigned short simg2[65 * ROW2];  // [a | x] (128 ic)
  __shared__ int so1[15], so2[15];
  __shared__ float smask[15];

  int b, i;
  decode_img(blockIdx.x, b, i);
  const int img = b * 16 + i;
  const int tid = threadIdx.x;
  const int w = tid >> 6, lane = tid & 63;

  if (tid < 15) {
    const int* gp = g_idx + ((size_t)b * 240 + i * 15 + tid) * 3;
    so1[tid] = gp[0] & 15;    // tile(x, n-1) => x1[j] = x[j & 15]
    so2[tid] = gp[1] & 15;
    smask[tid] = (float)gp[2];
  }
  // stage x -> simg2 ic rows 64..127 (independent of combine)
  {
    const int px = lane;
    const float* base = x + (size_t)img * IMGSZ;
#pragma unroll
    for (int r = 0; r < 4; ++r) {
      int ic0 = (w + 8 * r) * 2;
      const float* s = base + ic0 * 64;
      float a = s[px], c = s[64 + px];
      *(unsigned*)(simg2 + px * ROW2 + 64 + ic0) =
          (unsigned)f2bf(a) | ((unsigned)f2bf(c) << 16);
    }
  }
  if (tid < ROW / 2) ((unsigned*)simg)[(64 * ROW) / 2 + tid] = 0;
  if (tid < ROW2 / 2) ((unsigned*)simg2)[(64 * ROW2) / 2 + tid] = 0;
  __syncthreads();

  // ---- combine: pred = xs + sum_j relu(m*(cA[o1]+cB[o2])+b_rel); 8 elems/thread
  {
    const int e0 = tid * 8;                 // [px][ic] flat
    const size_t base_b = (size_t)b * 16 * IMGSZ;
    float acc[8], br[8];
    const float* xp = xs + (size_t)img * IMGSZ + e0;
    const int ic0 = e0 & 63;
#pragma unroll
    for (int u = 0; u < 8; ++u) acc[u] = xp[u];
#pragma unroll
    for (int u = 0; u < 8; ++u) br[u] = b_rel[ic0 + u];
#pragma unroll 5
    for (int jj = 0; jj < 15; ++jj) {
      const float* a1 = cA + base_b + (size_t)so1[jj] * IMGSZ + e0;
      const float* a2 = cB + base_b + (size_t)so2[jj] * IMGSZ + e0;
      float m = smask[jj];
#pragma unroll
      for (int u = 0; u < 8; ++u) {
        float v = m * (a1[u] + a2[u]) + br[u];
        acc[u] += fmaxf(v, 0.f);
      }
    }
    u16x8 p;
#pragma unroll
    for (int u = 0; u < 8; ++u) p[u] = f2bf(acc[u]);
    *(u16x8*)(simg + (e0 >> 6) * ROW + ic0) = p;
  }
  __syncthreads();

  const int q = lane >> 4, n16 = lane & 15;
  const int ocb = (w >> 1) * 16;
  const int pxb = (w & 1) * 32;
  const int px0 = pxb + n16, px1 = px0 + 16;
  const int py0 = px0 >> 3, pxx0 = px0 & 7;
  const int py1 = px1 >> 3, pxx1 = px1 & 7;
  const int co = ocb + q * 4;

  // ---- aff conv: simg -> a -> simg2 ic rows 0..63
  {
    f32x4 c0{}, c1{};
    const unsigned short* WAff = Wt + 3 * 36864 + (ocb + n16) * 64 + q * 8;
#pragma unroll
    for (int tap = 0; tap < 9; ++tap) {
      const int dy = tap / 3 - 1, dx = tap % 3 - 1;
      int sy0 = py0 + dy, sx0 = pxx0 + dx;
      int sy1 = py1 + dy, sx1 = pxx1 + dx;
      int sp0 = ((unsigned)sy0 < 8u && (unsigned)sx0 < 8u) ? (sy0 * 8 + sx0) : 64;
      int sp1 = ((unsigned)sy1 < 8u && (unsigned)sx1 < 8u) ? (sy1 * 8 + sx1) : 64;
#pragma unroll
      for (int ks = 0; ks < 2; ++ks) {
        bf16x8 b0 = *(const bf16x8*)(simg + sp0 * ROW + q * 8 + ks * 32);
        bf16x8 b1 = *(const bf16x8*)(simg + sp1 * ROW + q * 8 + ks * 32);
        bf16x8 a  = *(const bf16x8*)(WAff + tap * 4096 + ks * 32);
        c0 = __builtin_amdgcn_mfma_f32_16x16x32_bf16(a, b0, c0, 0, 0, 0);
        c1 = __builtin_amdgcn_mfma_f32_16x16x32_bf16(a, b1, c1, 0, 0, 0);
      }
    }
    uint2 pk0, pk1;
    float v0, v1, v2, v3;
    v0 = fmaxf(c0[0] + b_aff[co + 0], 0.f);
    v1 = fmaxf(c0[1] + b_aff[co + 1], 0.f);
    v2 = fmaxf(c0[2] + b_aff[co + 2], 0.f);
    v3 = fmaxf(c0[3] + b_aff[co + 3], 0.f);
    pk0.x = (unsigned)f2bf(v0) | ((unsigned)f2bf(v1) << 16);
    pk0.y = (unsigned)f2bf(v2) | ((unsigned)f2bf(v3) << 16);
    v0 = fmaxf(c1[0] + b_aff[co + 0], 0.f);
    v1 = fmaxf(c1[1] + b_aff[co + 1], 0.f);
    v2 = fmaxf(c1[2] + b_aff[co + 2], 0.f);
    v3 = fmaxf(c1[3] + b_aff[co + 3], 0.f);
    pk1.x = (unsigned)f2bf(v0) | ((unsigned)f2bf(v1) << 16);
    pk1.y = (unsigned)f2bf(v2) | ((unsigned)f2bf(v3) << 16);
    *(uint2*)(simg2 + px0 * ROW2 + co) = pk0;
    *(uint2*)(simg2 + px1 * ROW2 + co) = pk1;
  }
  __syncthreads();

  // ---- agg conv: simg2 (128 ic) -> out (fp32 [ic][px])
  {
    f32x4 g0{}, g1{};
    const unsigned short* WAgg = Wt + 4 * 36864 + (ocb + n16) * 128 + q * 8;
#pragma unroll
    for (int tap = 0; tap < 9; ++tap) {
      const int dy = tap / 3 - 1, dx = tap % 3 - 1;
      int sy0 = py0 + dy, sx0 = pxx0 + dx;
      int sy1 = py1 + dy, sx1 = pxx1 + dx;
      int sp0 = ((unsigned)sy0 < 8u && (unsigned)sx0 < 8u) ? (sy0 * 8 + sx0) : 64;
      int sp1 = ((unsigned)sy1 < 8u && (unsigned)sx1 < 8u) ? (sy1 * 8 + sx1) : 64;
#pragma unroll
      for (int ks = 0; ks < 4; ++ks) {
        bf16x8 b0 = *(const bf16x8*)(simg2 + sp0 * ROW2 + q * 8 + ks * 32);
        bf16x8 b1 = *(const bf16x8*)(simg2 + sp1 * ROW2 + q * 8 + ks * 32);
        bf16x8 a  = *(const bf16x8*)(WAgg + tap * 8192 + ks * 32);
        g0 = __builtin_amdgcn_mfma_f32_16x16x32_bf16(a, b0, g0, 0, 0, 0);
        g1 = __builtin_amdgcn_mfma_f32_16x16x32_bf16(a, b1, g1, 0, 0, 0);
      }
    }
    float* ob = out + (size_t)img * IMGSZ;
#pragma unroll
    for (int r = 0; r < 4; ++r) {
      int oc = co + r;
      float bv = b_agg[oc];
      ob[oc * 64 + px0] = fmaxf(g0[r] + bv, 0.f);
      ob[oc * 64 + px1] = fmaxf(g1[r] + bv, 0.f);
    }
  }
}

extern "C" void kernel_launch(void* const* d_in, const int* in_sizes, int n_in,
                              void* d_out, int out_size, void* d_ws, size_t ws_size,
                              hipStream_t stream) {
  const float* x      = (const float*)d_in[0];
  const int*   g_idx  = (const int*)  d_in[1];
  const float* W_rel  = (const float*)d_in[2];
  const float* b_rel  = (const float*)d_in[3];
  const float* W_self = (const float*)d_in[4];
  const float* b_self = (const float*)d_in[5];
  const float* W_aff  = (const float*)d_in[6];
  const float* b_aff  = (const float*)d_in[7];
  const float* W_agg  = (const float*)d_in[8];
  const float* b_agg  = (const float*)d_in[9];
  float* out = (float*)d_out;

  float* ws = (float*)d_ws;
  float* xs = ws;                          // [512][64px][64ic] fp32
  float* cA = ws + 2097152;
  float* cB = ws + 2 * 2097152;
  unsigned short* Wt = (unsigned short*)(ws + 3 * 2097152);  // 221184 bf16

  prep_weights<<<864, 256, 0, stream>>>(W_rel, W_self, W_aff, W_agg, Wt);
  k1_convs<<<NIMG, 512, 0, stream>>>(x, Wt, b_self, xs, cA, cB);
  k2_fused<<<NIMG, 512, 0, stream>>>(x, g_idx, Wt, b_rel, b_aff, b_agg,
                                     xs, cA, cB, out);
}